// Round 9
// baseline (11348.291 us; speedup 1.0000x reference)
//
#include <hip/hip_runtime.h>

// ---------------------------------------------------------------------------
// 2-layer LSTM, T=512 B=32 I=512 H=1024 — persistent kernel, 2 groups x 64 WG.
// R9: minimal-surface restructure. Keeps R7/R8's full-K in-wave accumulation
// (eliminates R1-R6's part[] K-split = the 1.3e8 LDS-conflict-cycle source,
// proven by R6's falsified prediction) but drops rings/producer groups/exotic
// asm. Only R2-R6-proven primitives:
//   - write-once h slots: producer global_store_dword sc0 sc1 + vmcnt(0)
//     drain + flag; consumer polls flag then NORMAL cached loads.
//   - polls: single asm global_load + s_waitcnt vmcnt(0).
// Groups: A (wg 0-63) layer0: Whh0 in LDS; x-part (x f32 inline-cvt @ Wxh0
// bf16 from L2) accumulated PRE-GO; h-part post-GO. C (wg 64-127) layer1:
// Whh1 in LDS; xg1-part (h0(s) @ Wxh1 bf16) pre-GO self-gated by flag0 poll
// (A runs ahead -> instant); h1-part post-GO.
// 12 waves: 0-7 MFMA tiles (m=wid>>2 batch-half, g=wid&3 gate), 8-9 gate
// math + h store + flag, 10 self-flag poller, 11 spare. Pre-GO work of step
// s+1 overlaps the gate/store/flag phase of step s.
// ---------------------------------------------------------------------------

typedef unsigned short u16;
typedef __attribute__((ext_vector_type(8))) __bf16 bf16x8;
typedef __attribute__((ext_vector_type(8))) u16 u16x8;
typedef __attribute__((ext_vector_type(4))) float f32x4;
typedef __attribute__((ext_vector_type(4))) int i32x4;
typedef __attribute__((ext_vector_type(4))) unsigned int u32x4;

#define HN_OFF 16777216   // 512*32*1024
#define CN_OFF 16842752   // HN_OFF + 2*32*1024

__device__ __forceinline__ u16 f2bf(float f) {   // RNE f32 -> bf16 (finite)
  unsigned u = __builtin_bit_cast(unsigned, f);
  u += 0x7FFFu + ((u >> 16) & 1u);
  return (u16)(u >> 16);
}
__device__ __forceinline__ float sgm(float x) { return 1.f / (1.f + __expf(-x)); }
__device__ __forceinline__ float tnh(float x) { return 2.f / (1.f + __expf(-2.f * x)) - 1.f; }

__device__ __forceinline__ bf16x8 ld16(const u16* p) {            // normal cached
  u32x4 v = *reinterpret_cast<const u32x4*>(p);
  return __builtin_bit_cast(bf16x8, v);
}
__device__ __forceinline__ bf16x8 lds16(const char* p) {
  u32x4 v = *reinterpret_cast<const u32x4*>(p);
  return __builtin_bit_cast(bf16x8, v);
}
__device__ __forceinline__ f32x4 mfma16(bf16x8 a, bf16x8 b, f32x4 c) {
  return __builtin_amdgcn_mfma_f32_16x16x32_bf16(a, b, c, 0, 0, 0);
}
__device__ __forceinline__ bf16x8 cvt8(const float* src) {        // 8 f32 -> bf16x8
  f32x4 lo = *reinterpret_cast<const f32x4*>(src);
  f32x4 hi = *reinterpret_cast<const f32x4*>(src + 4);
  u16x8 o;
  o[0]=f2bf(lo[0]); o[1]=f2bf(lo[1]); o[2]=f2bf(lo[2]); o[3]=f2bf(lo[3]);
  o[4]=f2bf(hi[0]); o[5]=f2bf(hi[1]); o[6]=f2bf(hi[2]); o[7]=f2bf(hi[3]);
  return __builtin_bit_cast(bf16x8, o);
}
__device__ __forceinline__ void cvt8store(char* dst, const float* src) {
  *reinterpret_cast<u16x8*>(dst) = __builtin_bit_cast(u16x8, cvt8(src));
}
__device__ __forceinline__ void st_coh(int* p, int v) {           // bypass L1/L2
  asm volatile("global_store_dword %0, %1, off sc0 sc1" :: "v"(p), "v"(v) : "memory");
}
// Poll 128-int flag array (8 lines): lanes 0-31 cover it (dup for 32-63).
__device__ __forceinline__ void poll128(const int* f, int lane, int thr) {
  const int* p = f + ((lane & 31) << 2);
  for (;;) {
    i32x4 v;
    asm volatile("global_load_dwordx4 %0, %1, off sc0 sc1\n\ts_waitcnt vmcnt(0)"
                 : "=v"(v) : "v"(p) : "memory");
    if (__all((v[0] >= thr) & (v[1] >= thr) & (v[2] >= thr) & (v[3] >= thr))) break;
  }
}

// LDS (dynamic, 139520 B):
//   [0, 131072)       Whh slice, fragment-ordered [g][c][lane*16B]: 4x32x1KB
//   [131072, 139264)  gates_lds[8 waves][16 b][16 n] f32 (8KB)
//   [139264, 139520)  bias[64] f32  (rows gate*16+n -> gate*1024 + w*16 + n)
__global__ __launch_bounds__(768, 2) void lstm2(
    const float* __restrict__ x,
    const u16* __restrict__ wxh0b, const u16* __restrict__ wxh1b,
    const float* __restrict__ Whh0, const float* __restrict__ Whh1,
    const float* __restrict__ bxh0, const float* __restrict__ bhh0,
    const float* __restrict__ bxh1, const float* __restrict__ bhh1,
    u16* __restrict__ h0seq, u16* __restrict__ h1seq,
    int* __restrict__ flag0, int* __restrict__ flag1,
    float* __restrict__ out) {
  extern __shared__ char smem[];
  float* gates_lds = reinterpret_cast<float*>(smem + 131072);
  float* bias_lds  = reinterpret_cast<float*>(smem + 139264);

  const int tid = threadIdx.x, wgid = blockIdx.x;
  const int grp = wgid >> 6, w = wgid & 63;
  const int wid = tid >> 6, lane = tid & 63;
  const int m = wid >> 2, g = wid & 3;            // MFMA waves (wid<8)
  const int r = lane & 15, kq = (lane >> 4) << 3;
  const int bl = lane >> 2, j4 = (lane & 3) << 2; // gate-wave mapping

  // ---- LDS fill: Whh slice bf16, fragment order (granule (gg,c,l)).
  const float* W = grp ? Whh1 : Whh0;
  for (int i = tid; i < 8192; i += 768) {
    int gg = i >> 11, c = (i >> 6) & 31, l = i & 63;
    const float* src = W + (size_t)(gg * 1024 + w * 16 + (l & 15)) * 1024
                         + c * 32 + ((l >> 4) << 3);
    cvt8store(smem + (((gg << 5) + c) << 10) + (l << 4), src);
  }
  if (tid < 64) {
    int row = (tid >> 4) * 1024 + w * 16 + (tid & 15);
    bias_lds[tid] = grp ? (bxh1[row] + bhh1[row]) : (bxh0[row] + bhh0[row]);
  }
  __syncthreads();

  u16* hseq  = grp ? h1seq : h0seq;
  int* fSelf = grp ? flag1 : flag0;
  const char* wbase = smem + ((g << 5) << 10) + (lane << 4);

  f32x4 bs0 = {0,0,0,0}, bs1 = bs0, bs2 = bs0, bs3 = bs0;
  float cst[4] = {0.f, 0.f, 0.f, 0.f};
  if (wid == 8 || wid == 9) {
    bs0 = *reinterpret_cast<const f32x4*>(&bias_lds[ 0 + j4]);
    bs1 = *reinterpret_cast<const f32x4*>(&bias_lds[16 + j4]);
    bs2 = *reinterpret_cast<const f32x4*>(&bias_lds[32 + j4]);
    bs3 = *reinterpret_cast<const f32x4*>(&bias_lds[48 + j4]);
  }

  for (int s = 0; s < 512; ++s) {
    f32x4 acc = {0.f, 0.f, 0.f, 0.f};
    if (wid < 8) {
      if (grp == 0) {      // ---- pre-GO x-part: x(s) @ Wxh0, K=512 (static data)
        const float* xs = x + (size_t)(s * 32 + m * 16 + r) * 512 + kq;
        const u16* wx = wxh0b + (size_t)((g << 10) + w * 16 + r) * 512 + kq;
#pragma unroll
        for (int c = 0; c < 16; ++c)
          acc = mfma16(cvt8(xs + c * 32), ld16(wx + c * 32), acc);
      } else {             // ---- pre-GO xg1-part: h0(s) @ Wxh1 (flag0-gated, A ahead)
        poll128(flag0, lane, s + 1);
        const u16* hs0 = h0seq + (size_t)(s + 1) * 32768 + (size_t)(m * 16 + r) * 1024 + kq;
        const u16* wx = wxh1b + (size_t)((g << 10) + w * 16 + r) * 1024 + kq;
#pragma unroll
        for (int c = 0; c < 32; ++c)
          acc = mfma16(ld16(hs0 + c * 32), ld16(wx + c * 32), acc);
      }
    } else if (wid == 10) {
      poll128(fSelf, lane, s);       // own-layer recurrence dependency
    }
    __syncthreads();                 // GO

    if (wid < 8) {                   // ---- h-part: h(s) @ Whh (LDS), K=1024
      const u16* hs = hseq + (size_t)s * 32768 + (size_t)(m * 16 + r) * 1024 + kq;
#pragma unroll
      for (int c = 0; c < 32; ++c)
        acc = mfma16(ld16(hs + c * 32), lds16(wbase + (c << 10)), acc);
      float* gl = gates_lds + (wid << 8);   // D-frag: b=(lane>>4)*4+j, n=r
#pragma unroll
      for (int jj = 0; jj < 4; ++jj)
        gl[(((lane >> 4) << 2) + jj) * 16 + r] = acc[jj];
    }
    __syncthreads();                 // ACC

    if (wid == 8 || wid == 9) {      // ---- gates: m2 half, lane=(bl, j4..+3)
      const int m2 = wid & 1;
      const int base = (m2 << 2) * 256 + bl * 16 + j4;
      f32x4 vi = *reinterpret_cast<const f32x4*>(&gates_lds[base]);
      f32x4 vf = *reinterpret_cast<const f32x4*>(&gates_lds[base + 256]);
      f32x4 vg = *reinterpret_cast<const f32x4*>(&gates_lds[base + 512]);
      f32x4 vo = *reinterpret_cast<const f32x4*>(&gates_lds[base + 768]);
      float hv[4];
#pragma unroll
      for (int k = 0; k < 4; ++k) {
        cst[k] = sgm(vf[k] + bs1[k]) * cst[k] + sgm(vi[k] + bs0[k]) * tnh(vg[k] + bs2[k]);
        hv[k]  = sgm(vo[k] + bs3[k]) * tnh(cst[k]);
      }
      int p0 = (int)((unsigned)f2bf(hv[0]) | ((unsigned)f2bf(hv[1]) << 16));
      int p1 = (int)((unsigned)f2bf(hv[2]) | ((unsigned)f2bf(hv[3]) << 16));
      u16* hp = hseq + (size_t)(s + 1) * 32768 + (size_t)(m2 * 16 + bl) * 1024 + w * 16 + j4;
      st_coh(reinterpret_cast<int*>(hp), p0);
      st_coh(reinterpret_cast<int*>(hp) + 1, p1);
      if (grp)                        // layer1 hidden sequence -> out (f32)
        *reinterpret_cast<f32x4*>(out + (size_t)s * 32768 + (m2 * 16 + bl) * 1024 + w * 16 + j4)
            = f32x4{hv[0], hv[1], hv[2], hv[3]};
      if (s == 511) {
        const int lofs = grp ? 32768 : 0;
        *reinterpret_cast<f32x4*>(out + HN_OFF + lofs + (m2 * 16 + bl) * 1024 + w * 16 + j4)
            = f32x4{hv[0], hv[1], hv[2], hv[3]};
        *reinterpret_cast<f32x4*>(out + CN_OFF + lofs + (m2 * 16 + bl) * 1024 + w * 16 + j4)
            = f32x4{cst[0], cst[1], cst[2], cst[3]};
      }
      asm volatile("s_waitcnt vmcnt(0)" ::: "memory");   // h at fabric before flag
      if (lane == 0) st_coh(fSelf + (m2 << 6) + w, s + 1);
    }
  }
}

__global__ void cvt_bf16(const float* __restrict__ s, u16* __restrict__ d, int n) {
  int i = (blockIdx.x * blockDim.x + threadIdx.x) * 4;
  const int stride = gridDim.x * blockDim.x * 4;
  typedef __attribute__((ext_vector_type(4))) u16 u16x4;
  for (; i < n; i += stride) {
    f32x4 v = *reinterpret_cast<const f32x4*>(s + i);
    u16x4 o;
    o[0] = f2bf(v[0]); o[1] = f2bf(v[1]); o[2] = f2bf(v[2]); o[3] = f2bf(v[3]);
    *reinterpret_cast<u16x4*>(d + i) = o;
  }
}

// ws layout (bytes):
//   wxh0b [0, 4194304)             Wxh0 bf16 row-major (4096 x 512)
//   wxh1b [4194304, 12582912)      Wxh1 bf16 row-major (4096 x 1024)
//   h0seq [12582912, 46202880)     513 slots x 64KB bf16, write-once
//   h1seq [46202880, 79822848)
//   flag0 [79822848, +512)  flag1 [79823360, +512)   total 79,823,872
extern "C" void kernel_launch(void* const* d_in, const int* in_sizes, int n_in,
                              void* d_out, int out_size, void* d_ws, size_t ws_size,
                              hipStream_t stream) {
  const float* x    = (const float*)d_in[0];
  const float* Wxh0 = (const float*)d_in[1];
  const float* bxh0 = (const float*)d_in[2];
  const float* Whh0 = (const float*)d_in[3];
  const float* bhh0 = (const float*)d_in[4];
  const float* Wxh1 = (const float*)d_in[5];
  const float* bxh1 = (const float*)d_in[6];
  const float* Whh1 = (const float*)d_in[7];
  const float* bhh1 = (const float*)d_in[8];
  char* ws = (char*)d_ws;
  u16* wxh0b = (u16*)(ws);
  u16* wxh1b = (u16*)(ws + 4194304);
  u16* h0seq = (u16*)(ws + 12582912);
  u16* h1seq = (u16*)(ws + 46202880);
  int* flag0 = (int*)(ws + 79822848);
  int* flag1 = (int*)(ws + 79823360);

  cvt_bf16<<<1024, 256, 0, stream>>>(Wxh0, wxh0b, 4096 * 512);
  cvt_bf16<<<1024, 256, 0, stream>>>(Wxh1, wxh1b, 4096 * 1024);
  (void)hipMemsetAsync(h0seq, 0, 65536, stream);    // h0 slot0 = zeros
  (void)hipMemsetAsync(h1seq, 0, 65536, stream);    // h1 slot0 = zeros
  (void)hipMemsetAsync(flag0, 0, 1024, stream);     // flag0 + flag1

  (void)hipFuncSetAttribute(reinterpret_cast<const void*>(lstm2),
                            hipFuncAttributeMaxDynamicSharedMemorySize, 139520);
  lstm2<<<dim3(128), dim3(768), 139520, stream>>>(
      x, wxh0b, wxh1b, Whh0, Whh1, bxh0, bhh0, bxh1, bhh1,
      h0seq, h1seq, flag0, flag1, (float*)d_out);
}

// Round 10
// 4397.041 us; speedup vs baseline: 2.5809x; 2.5809x over previous
//
#include <hip/hip_runtime.h>

// ---------------------------------------------------------------------------
// 2-layer LSTM, T=512 B=32 I=512 H=1024 — persistent kernel, layer-pipelined.
// R10: FLAG-FREE data-driven sync. R2-R9 showed the wall is the hop count of
// the flag protocol (store->drain->flag->detect->load ~4 fabric RTs/step).
// Now: h slots write-once, pre-filled 0xFF (bf16 NaN sentinel); consumers
// load h with sc0|sc1 (fresh from L3) in a retry loop until non-sentinel —
// the data load IS the sync. Producers store h sc0|sc1, no drain, no flag.
//   - forced-batch loads: inline-asm 8x global_load_dwordx4 per block
//     (SGPR base + voffset + offset:imm), 16 in flight/wave; one vmcnt(0) +
//     sched_barrier(0) (rule #18) + sentinel check; rare re-issue + s_sleep.
//   - x-proj (waves 4,6,7) computed during the GATE phase of the previous
//     step (overlapped, not serial — R9's mistake).
//   - compute structure = R3 verbatim (8 waves, dual-B h0, K-split part[],
//     gates on wave1/wave5, 2 intra-WG barriers/step). 256 WGs, 1/CU.
// ---------------------------------------------------------------------------

typedef unsigned short u16;
typedef __attribute__((ext_vector_type(8))) __bf16 bf16x8;
typedef __attribute__((ext_vector_type(8))) u16 u16x8;
typedef __attribute__((ext_vector_type(4))) float f32x4;
typedef __attribute__((ext_vector_type(2))) float f32x2;
typedef __attribute__((ext_vector_type(4))) unsigned int u32x4;

#define HN_OFF 16777216   // 512*32*1024
#define CN_OFF 16842752   // HN_OFF + 2*32*1024
#define SENTU 0xFFFFFFFFu // 2x bf16 NaN — unreachable for real h in (-1,1)

__device__ __forceinline__ u16 f2bf(float f) {   // RNE f32 -> bf16 (finite)
  unsigned u = __builtin_bit_cast(unsigned, f);
  u += 0x7FFFu + ((u >> 16) & 1u);
  return (u16)(u >> 16);
}
__device__ __forceinline__ float sgm(float x) { return 1.f / (1.f + __expf(-x)); }
__device__ __forceinline__ float tnh(float x) { return 2.f / (1.f + __expf(-2.f * x)) - 1.f; }

__device__ __forceinline__ bf16x8 ld16(const u16* p) {            // normal cached
  u32x4 v = *reinterpret_cast<const u32x4*>(p);
  return __builtin_bit_cast(bf16x8, v);
}
__device__ __forceinline__ bf16x8 lds16(const char* p) {
  u32x4 v = *reinterpret_cast<const u32x4*>(p);
  return __builtin_bit_cast(bf16x8, v);
}
__device__ __forceinline__ f32x4 mfma16(bf16x8 a, bf16x8 b, f32x4 c) {
  return __builtin_amdgcn_mfma_f32_16x16x32_bf16(a, b, c, 0, 0, 0);
}

// 8 coherent 16B loads: SGPR base + lane voffset, chunk-stride 64B immediates.
#define LD8A(a,b,c,d_,e,f,g,h,off,bs)                                   \
  asm volatile("global_load_dwordx4 %0, %8, %9 offset:0 sc0 sc1\n\t"    \
               "global_load_dwordx4 %1, %8, %9 offset:64 sc0 sc1\n\t"   \
               "global_load_dwordx4 %2, %8, %9 offset:128 sc0 sc1\n\t"  \
               "global_load_dwordx4 %3, %8, %9 offset:192 sc0 sc1\n\t"  \
               "global_load_dwordx4 %4, %8, %9 offset:256 sc0 sc1\n\t"  \
               "global_load_dwordx4 %5, %8, %9 offset:320 sc0 sc1\n\t"  \
               "global_load_dwordx4 %6, %8, %9 offset:384 sc0 sc1\n\t"  \
               "global_load_dwordx4 %7, %8, %9 offset:448 sc0 sc1"      \
               : "=&v"(a), "=&v"(b), "=&v"(c), "=&v"(d_), "=&v"(e),     \
                 "=&v"(f), "=&v"(g), "=&v"(h)                           \
               : "v"(off), "s"(bs) : "memory")

#define DECL16 u32x4 d0,d1,d2,d3,d4,d5,d6,d7,d8,d9,d10,d11,d12,d13,d14,d15
#define CHK(v) (((v)[0]==SENTU)|((v)[1]==SENTU)|((v)[2]==SENTU)|((v)[3]==SENTU))
// retry until all 16 fragments are non-sentinel (write-once slots => final).
#define RETRY16(bs,o0,o1)                                                   \
  for (;;) {                                                                \
    LD8A(d0,d1,d2,d3,d4,d5,d6,d7,(o0),(bs));                                \
    LD8A(d8,d9,d10,d11,d12,d13,d14,d15,(o1),(bs));                          \
    asm volatile("s_waitcnt vmcnt(0)" ::: "memory");                        \
    __builtin_amdgcn_sched_barrier(0);                                      \
    unsigned bad = CHK(d0)|CHK(d1)|CHK(d2)|CHK(d3)|CHK(d4)|CHK(d5)|CHK(d6)  \
                 |CHK(d7)|CHK(d8)|CHK(d9)|CHK(d10)|CHK(d11)|CHK(d12)        \
                 |CHK(d13)|CHK(d14)|CHK(d15);                               \
    if (!__any(bad)) break;                                                 \
    __builtin_amdgcn_s_sleep(1);                                            \
  }

// dual-B L0 chunk: a-pair feeds Whh0 (p) and Wxh1 chunk c+32 (q)
#define MM_L0(di,dj,c) {                                                    \
    bf16x8 b0 = lds16(w0 + r*3072 + (((c)*64 + kq2) ^ swz));                \
    bf16x8 b1 = lds16(w1 + r*4096 + ((((c)+32)*64 + kq2) ^ swz));           \
    bf16x8 a0 = __builtin_bit_cast(bf16x8, di);                             \
    bf16x8 a1 = __builtin_bit_cast(bf16x8, dj);                             \
    p0 = mfma16(a0,b0,p0);  p1 = mfma16(a1,b0,p1);                          \
    qa = mfma16(a0,b1,qa);  qb = mfma16(a1,b1,qb); }
#define MM_L1(di,dj,c) {                                                    \
    bf16x8 bw = lds16(w1 + r*4096 + (((c)*64 + kq2) ^ swz));                \
    p0 = mfma16(__builtin_bit_cast(bf16x8, di), bw, p0);                    \
    p1 = mfma16(__builtin_bit_cast(bf16x8, dj), bw, p1); }

// x-projection chunks (normal cached loads; static data)
template <int C0, int C1>
__device__ __forceinline__ void chunks_x(const u16* __restrict__ A,
                                         const char* w0, int lane,
                                         f32x4& q0, f32x4& q1) {
  const int r = lane & 15, kq = (lane >> 4) * 8, swz = (r & 7) << 4;
#pragma unroll
  for (int c = C0; c < C1; ++c) {
    const u16* ap = A + r * 512 + c * 32 + kq;
    bf16x8 a0 = ld16(ap);
    bf16x8 a1 = ld16(ap + 16 * 512);
    bf16x8 bw = lds16(w0 + r * 3072 + (((c + 32) * 64 + kq * 2) ^ swz));
    q0 = mfma16(a0, bw, q0);  q1 = mfma16(a1, bw, q1);
  }
}

// LDS (dynamic, 151680 B):
//   [0,      49152)  w0: 16 rows x 1536 bf16 [Whh0|Wxh0], XOR-swizzled
//   [49152, 114688)  w1: 16 rows x 2048 bf16 [Whh1|Wxh1], XOR-swizzled
//   [114688,151552)  part[16][32][18] f32 (0-3 L0h0, 4-7 L1h1, 8-11 L1xg, 12-15 L0x)
//   [151552]bias0[16]  [151616]bias1[16]
__global__ __launch_bounds__(512, 2) void lstm_fused(
    const u16* __restrict__ xbf,
    const float* __restrict__ Whh0, const float* __restrict__ Wxh0,
    const float* __restrict__ Whh1, const float* __restrict__ Wxh1,
    const float* __restrict__ bxh0, const float* __restrict__ bhh0,
    const float* __restrict__ bxh1, const float* __restrict__ bhh1,
    u16* __restrict__ h0seq, u16* __restrict__ h1seq,
    float* __restrict__ out) {
  extern __shared__ char smem[];
  const char* w0 = smem;
  const char* w1 = smem + 49152;
  auto part = reinterpret_cast<float(*)[32][18]>(smem + 114688);
  float* bias0 = reinterpret_cast<float*>(smem + 151552);
  float* bias1 = reinterpret_cast<float*>(smem + 151616);

  const int tid = threadIdx.x;
  const int wg = blockIdx.x;
  const int wid = tid >> 6, lane = tid & 63;
  const int r = lane & 15, kq2 = ((lane >> 4) << 3) * 2, swz = (r & 7) << 4;

  // ---- LDS weight fill (R3-verbatim maps, f32 -> bf16 inline)
  for (int g = tid; g < 3072; g += 512) {
    int n = g / 192, gi = g % 192, kc = gi * 8;
    int gr = ((n >> 2) << 10) + (wg << 2) + (n & 3);
    const float* src = (kc < 1024) ? (Whh0 + gr * 1024 + kc) : (Wxh0 + gr * 512 + (kc - 1024));
    f32x4 lo = *reinterpret_cast<const f32x4*>(src);
    f32x4 hi = *reinterpret_cast<const f32x4*>(src + 4);
    u16x8 o;
    o[0]=f2bf(lo[0]); o[1]=f2bf(lo[1]); o[2]=f2bf(lo[2]); o[3]=f2bf(lo[3]);
    o[4]=f2bf(hi[0]); o[5]=f2bf(hi[1]); o[6]=f2bf(hi[2]); o[7]=f2bf(hi[3]);
    *reinterpret_cast<u16x8*>(smem + n * 3072 + ((gi * 16) ^ ((n & 7) << 4))) = o;
  }
  for (int g = tid; g < 4096; g += 512) {
    int n = g / 256, gi = g % 256, kc = gi * 8;
    int gr = ((n >> 2) << 10) + (wg << 2) + (n & 3);
    const float* src = (kc < 1024) ? (Whh1 + gr * 1024 + kc) : (Wxh1 + gr * 1024 + (kc - 1024));
    f32x4 lo = *reinterpret_cast<const f32x4*>(src);
    f32x4 hi = *reinterpret_cast<const f32x4*>(src + 4);
    u16x8 o;
    o[0]=f2bf(lo[0]); o[1]=f2bf(lo[1]); o[2]=f2bf(lo[2]); o[3]=f2bf(lo[3]);
    o[4]=f2bf(hi[0]); o[5]=f2bf(hi[1]); o[6]=f2bf(hi[2]); o[7]=f2bf(hi[3]);
    *reinterpret_cast<u16x8*>(smem + 49152 + n * 4096 + ((gi * 16) ^ ((n & 7) << 4))) = o;
  }
  if (tid < 16) {
    int gr = ((tid >> 2) << 10) + (wg << 2) + (tid & 3);
    bias0[tid] = bxh0[gr] + bhh0[gr];
    bias1[tid] = bxh1[gr] + bhh1[gr];
  }
  __syncthreads();

  float c0a = 0.f, c0b = 0.f, c1a = 0.f, c1b = 0.f;   // cell state (wave1/wave5)
  const int bg = lane >> 1, jjb = (lane & 1) << 1;    // gate-math mapping
  const int colb = (wg << 2) + jjb;

  // persistent x-projection accumulators (waves 4,6,7), prologue = x(0)
  f32x4 xq0 = {0,0,0,0}, xq1 = {0,0,0,0};
  if      (wid == 4) chunks_x<0, 6 >(xbf, w0, lane, xq0, xq1);
  else if (wid == 6) chunks_x<6, 11>(xbf, w0, lane, xq0, xq1);
  else if (wid == 7) chunks_x<11,16>(xbf, w0, lane, xq0, xq1);

  for (int s = 0; s <= 512; ++s) {
    f32x4 p0 = {0,0,0,0}, p1 = {0,0,0,0}, qa = {0,0,0,0}, qb = {0,0,0,0};

    // ---- phase R: sentinel-retry h loads + MFMA
    if (wid < 4) {                     // L0: h0slot(s) dual-B, chunks wid*8..+8
      const u16* hb = h0seq + (size_t)s * 32768;
      const int off0 = r * 2048 + wid * 512 + kq2;
      const int off1 = off0 + 32768;
      DECL16;
      RETRY16(hb, off0, off1);
      const int c0 = wid * 8;
      MM_L0(d0, d8,  c0 + 0); MM_L0(d1, d9,  c0 + 1);
      MM_L0(d2, d10, c0 + 2); MM_L0(d3, d11, c0 + 3);
      MM_L0(d4, d12, c0 + 4); MM_L0(d5, d13, c0 + 5);
      MM_L0(d6, d14, c0 + 6); MM_L0(d7, d15, c0 + 7);
    } else if (s >= 1) {               // L1: h1prev(s-1), chunks (wid-4)*8..+8
      const u16* hb = h1seq + (size_t)(s - 1) * 32768;
      const int off0 = r * 2048 + (wid - 4) * 512 + kq2;
      const int off1 = off0 + 32768;
      DECL16;
      RETRY16(hb, off0, off1);
      const int c0 = (wid - 4) * 8;
      MM_L1(d0, d8,  c0 + 0); MM_L1(d1, d9,  c0 + 1);
      MM_L1(d2, d10, c0 + 2); MM_L1(d3, d11, c0 + 3);
      MM_L1(d4, d12, c0 + 4); MM_L1(d5, d13, c0 + 5);
      MM_L1(d6, d14, c0 + 6); MM_L1(d7, d15, c0 + 7);
    }

    {   // ---- partial-sum write (D-frag: col=lane&15, row=(lane>>4)*4+j)
      const int n = lane & 15, br = (lane >> 4) * 4;
      const f32x4 q0 = (wid < 4) ? qa : xq0;
      const f32x4 q1 = (wid < 4) ? qb : xq1;
#pragma unroll
      for (int j = 0; j < 4; ++j) {
        part[wid][br + j][n]          = p0[j];
        part[wid][br + j + 16][n]     = p1[j];
        part[8 + wid][br + j][n]      = q0[j];
        part[8 + wid][br + j + 16][n] = q1[j];
      }
    }
    __syncthreads();                   // B1: parts readable

    // ---- phase G: gates (waves 1,5) || x(s+1) projection (waves 4,6,7)
    if (wid == 1) {                    // L0 gates (t0 = s)
      if (s < 512) {
        float v[4][2];
#pragma unroll
        for (int gi = 0; gi < 4; ++gi) {
          const int n = (gi << 2) + jjb;
          float s0 = bias0[n], s1 = bias0[n + 1];
#pragma unroll
          for (int p = 0; p < 4; ++p) {
            f32x2 a = *reinterpret_cast<const f32x2*>(&part[p][bg][n]);
            f32x2 b = *reinterpret_cast<const f32x2*>(&part[12 + p][bg][n]);
            s0 += a[0] + b[0];  s1 += a[1] + b[1];
          }
          v[gi][0] = s0; v[gi][1] = s1;
        }
        c0a = sgm(v[1][0]) * c0a + sgm(v[0][0]) * tnh(v[2][0]);
        c0b = sgm(v[1][1]) * c0b + sgm(v[0][1]) * tnh(v[2][1]);
        const float ha = sgm(v[3][0]) * tnh(c0a), hb = sgm(v[3][1]) * tnh(c0b);
        unsigned pk = (unsigned)f2bf(ha) | ((unsigned)f2bf(hb) << 16);
        u16* hp = h0seq + (size_t)(s + 1) * 32768 + bg * 1024 + colb;
        asm volatile("global_store_dword %0, %1, off sc0 sc1" :: "v"(hp), "v"(pk) : "memory");
        if (s == 511) {
          *reinterpret_cast<f32x2*>(out + HN_OFF + bg * 1024 + colb) = f32x2{ha, hb};
          *reinterpret_cast<f32x2*>(out + CN_OFF + bg * 1024 + colb) = f32x2{c0a, c0b};
        }
      }
    } else if (wid == 5) {             // L1 gates (t1 = s-1)
      if (s >= 1) {
        float v[4][2];
#pragma unroll
        for (int gi = 0; gi < 4; ++gi) {
          const int n = (gi << 2) + jjb;
          float s0 = bias1[n], s1 = bias1[n + 1];
#pragma unroll
          for (int p = 4; p < 12; ++p) {
            f32x2 a = *reinterpret_cast<const f32x2*>(&part[p][bg][n]);
            s0 += a[0];  s1 += a[1];
          }
          v[gi][0] = s0; v[gi][1] = s1;
        }
        c1a = sgm(v[1][0]) * c1a + sgm(v[0][0]) * tnh(v[2][0]);
        c1b = sgm(v[1][1]) * c1b + sgm(v[0][1]) * tnh(v[2][1]);
        const float ha = sgm(v[3][0]) * tnh(c1a), hb = sgm(v[3][1]) * tnh(c1b);
        unsigned pk = (unsigned)f2bf(ha) | ((unsigned)f2bf(hb) << 16);
        u16* hp = h1seq + (size_t)s * 32768 + bg * 1024 + colb;
        asm volatile("global_store_dword %0, %1, off sc0 sc1" :: "v"(hp), "v"(pk) : "memory");
        const int t1 = s - 1;
        *reinterpret_cast<f32x2*>(out + t1 * 32768 + bg * 1024 + colb) = f32x2{ha, hb};
        if (t1 == 511) {
          *reinterpret_cast<f32x2*>(out + HN_OFF + 32768 + bg * 1024 + colb) = f32x2{ha, hb};
          *reinterpret_cast<f32x2*>(out + CN_OFF + 32768 + bg * 1024 + colb) = f32x2{c1a, c1b};
        }
      }
    } else if (wid == 4 && s < 511) {  // x(s+1) proj, overlapped with gates
      xq0 = f32x4{0,0,0,0}; xq1 = f32x4{0,0,0,0};
      chunks_x<0, 6>(xbf + (size_t)(s + 1) * 16384, w0, lane, xq0, xq1);
    } else if (wid == 6 && s < 511) {
      xq0 = f32x4{0,0,0,0}; xq1 = f32x4{0,0,0,0};
      chunks_x<6, 11>(xbf + (size_t)(s + 1) * 16384, w0, lane, xq0, xq1);
    } else if (wid == 7 && s < 511) {
      xq0 = f32x4{0,0,0,0}; xq1 = f32x4{0,0,0,0};
      chunks_x<11, 16>(xbf + (size_t)(s + 1) * 16384, w0, lane, xq0, xq1);
    }

    if (s == 512) break;
    __syncthreads();                   // B2: gates done -> part[] reusable
  }
}

__global__ void cvt_bf16(const float* __restrict__ s, u16* __restrict__ d, int n) {
  int i = (blockIdx.x * blockDim.x + threadIdx.x) * 4;
  const int stride = gridDim.x * blockDim.x * 4;
  typedef __attribute__((ext_vector_type(4))) u16 u16x4;
  for (; i < n; i += stride) {
    f32x4 v = *reinterpret_cast<const f32x4*>(s + i);
    u16x4 o;
    o[0] = f2bf(v[0]); o[1] = f2bf(v[1]); o[2] = f2bf(v[2]); o[3] = f2bf(v[3]);
    *reinterpret_cast<u16x4*>(d + i) = o;
  }
}

// ws (bytes): xbf [0,16777216) | h0seq [16777216,+513*65536) | h1seq [50397184,+same)
// total 84,017,152. No flags.
extern "C" void kernel_launch(void* const* d_in, const int* in_sizes, int n_in,
                              void* d_out, int out_size, void* d_ws, size_t ws_size,
                              hipStream_t stream) {
  const float* x    = (const float*)d_in[0];
  const float* Wxh0 = (const float*)d_in[1];
  const float* bxh0 = (const float*)d_in[2];
  const float* Whh0 = (const float*)d_in[3];
  const float* bhh0 = (const float*)d_in[4];
  const float* Wxh1 = (const float*)d_in[5];
  const float* bxh1 = (const float*)d_in[6];
  const float* Whh1 = (const float*)d_in[7];
  const float* bhh1 = (const float*)d_in[8];
  char* ws = (char*)d_ws;
  u16* xbf   = (u16*)(ws);
  u16* h0seq = (u16*)(ws + 16777216);
  u16* h1seq = (u16*)(ws + 50397184);

  cvt_bf16<<<2048, 256, 0, stream>>>(x, xbf, 512 * 32 * 512);
  // slot 0 = zeros (initial h); slots 1..512 = 0xFF sentinel (re-armed every
  // launch/replay — part of the captured graph).
  (void)hipMemsetAsync(h0seq, 0, 65536, stream);
  (void)hipMemsetAsync((char*)h0seq + 65536, 0xFF, 512 * 65536, stream);
  (void)hipMemsetAsync(h1seq, 0, 65536, stream);
  (void)hipMemsetAsync((char*)h1seq + 65536, 0xFF, 512 * 65536, stream);

  (void)hipFuncSetAttribute(reinterpret_cast<const void*>(lstm_fused),
                            hipFuncAttributeMaxDynamicSharedMemorySize, 151680);
  lstm_fused<<<dim3(256), dim3(512), 151680, stream>>>(
      xbf, Whh0, Wxh0, Whh1, Wxh1, bxh0, bhh0, bxh1, bhh1,
      h0seq, h1seq, (float*)d_out);
}